// Round 2
// baseline (262.673 us; speedup 1.0000x reference)
//
#include <hip/hip_runtime.h>

// Closed-form reduction of the 2-qubit circuit:
//   z0(b,p,c) = cos(theta_c)*cos(a) - sin(theta_c)*sin(a)*sin(b)
//   z1(b,p)   = cos(a)*cos(b)                       (theta-independent)
//   out[b, p*14 + q*7 + c] = 0.5 + 0.5*z
// where a = x[b, pair[p].x], b = x[b, pair[p].y].

constexpr int NX = 1024;            // flattened features per batch row
constexpr int NP = 512;             // pairs
constexpr int NC = 7;               // classes
constexpr int OUT_PER_B = NP * 2 * NC;  // 7168
constexpr int THREADS = 256;

__global__ __launch_bounds__(THREADS) void fuzzy_qc_kernel(
    const float* __restrict__ x,
    const int2*  __restrict__ pairs,
    const float* __restrict__ theta,
    float*       __restrict__ out)
{
    __shared__ float s_ca[NP];   // cos(a)
    __shared__ float s_w[NP];    // sin(a)*sin(b)
    __shared__ float s_z1[NP];   // cos(a)*cos(b)
    __shared__ float s_ct[NC];   // cos(theta)
    __shared__ float s_st[NC];   // sin(theta)

    const int tid = threadIdx.x;
    const int b   = blockIdx.x;
    const float* xrow = x + (size_t)b * NX;

    // theta sincos (full angle) -> LDS
    if (tid < NC) {
        float t = theta[tid];
        float s, c;
        sincosf(t, &s, &c);
        s_ct[tid] = c;
        s_st[tid] = s;
    }

    // Stage A: per-pair precompute (2 pairs per thread)
#pragma unroll
    for (int k = 0; k < NP / THREADS; ++k) {
        int p = tid + k * THREADS;
        int2 pr = pairs[p];
        float av = xrow[pr.x];
        float bv = xrow[pr.y];
        float sa, ca, sb, cb;
        sincosf(av, &sa, &ca);
        sincosf(bv, &sb, &cb);
        s_ca[p] = ca;
        s_w[p]  = sa * sb;
        s_z1[p] = ca * cb;
    }

    __syncthreads();

    // Phase 2: coalesced float4 output writes (7168 floats per row)
    float4* out4 = reinterpret_cast<float4*>(out + (size_t)b * OUT_PER_B);
#pragma unroll
    for (int k = 0; k < OUT_PER_B / 4 / THREADS; ++k) {   // 7 iters
        int i4 = tid + k * THREADS;       // 0..1791
        int o  = i4 * 4;
        float r[4];
#pragma unroll
        for (int j = 0; j < 4; ++j) {
            unsigned e  = (unsigned)(o + j);
            unsigned p  = e / 14u;              // magic-mul division
            unsigned rr = e - p * 14u;
            bool     q1 = rr >= 7u;
            unsigned c  = q1 ? rr - 7u : rr;
            float ca  = s_ca[p];
            float w   = s_w[p];
            float z1  = s_z1[p];
            float z0  = s_ct[c] * ca - s_st[c] * w;
            float z   = q1 ? z1 : z0;
            r[j] = fmaf(0.5f, z, 0.5f);
        }
        out4[i4] = make_float4(r[0], r[1], r[2], r[3]);
    }
}

extern "C" void kernel_launch(void* const* d_in, const int* in_sizes, int n_in,
                              void* d_out, int out_size, void* d_ws, size_t ws_size,
                              hipStream_t stream) {
    const float* x     = (const float*)d_in[0];
    const int2*  pairs = (const int2*)d_in[1];
    const float* theta = (const float*)d_in[2];
    float*       out   = (float*)d_out;

    const int B = in_sizes[0] / NX;   // 8192
    fuzzy_qc_kernel<<<B, THREADS, 0, stream>>>(x, pairs, theta, out);
}

// Round 3
// 262.589 us; speedup vs baseline: 1.0003x; 1.0003x over previous
//
#include <hip/hip_runtime.h>

// Closed-form reduction of the 2-qubit circuit:
//   z0(b,p,c) = cos(theta_c)*cos(a) - sin(theta_c)*sin(a)*sin(b)
//   z1(b,p)   = cos(a)*cos(b)                       (theta-independent)
//   out[b, p*14 + q*7 + c] = 0.5 + 0.5*z
// where a = x[b, pair[p].x], b = x[b, pair[p].y].
//
// R3: __sinf/__cosf (native v_sin/v_cos — args are uniform[0,1) rad and
// theta~N(0,1), well inside HW range; tolerance 2e-2 vs ~1e-5 native error)
// + coalesced row staging into LDS so the pair-gather hits LDS, not L1.

constexpr int NX = 1024;            // flattened features per batch row
constexpr int NP = 512;             // pairs
constexpr int NC = 7;               // classes
constexpr int OUT_PER_B = NP * 2 * NC;  // 7168
constexpr int THREADS = 256;

__global__ __launch_bounds__(THREADS) void fuzzy_qc_kernel(
    const float* __restrict__ x,
    const int2*  __restrict__ pairs,
    const float* __restrict__ theta,
    float*       __restrict__ out)
{
    __shared__ float s_x[NX];    // staged input row (4 KB)
    __shared__ float s_ca[NP];   // cos(a)
    __shared__ float s_w[NP];    // sin(a)*sin(b)
    __shared__ float s_z1[NP];   // cos(a)*cos(b)
    __shared__ float s_ct[NC];   // cos(theta)
    __shared__ float s_st[NC];   // sin(theta)

    const int tid = threadIdx.x;
    const int b   = blockIdx.x;
    const float* xrow = x + (size_t)b * NX;

    // Coalesced row load -> LDS: 256 lanes x one float4 = 1024 floats.
    reinterpret_cast<float4*>(s_x)[tid] =
        reinterpret_cast<const float4*>(xrow)[tid];

    // theta sincos (libm; only 7 lanes, arbitrary range) -> LDS
    if (tid < NC) {
        float t = theta[tid];
        float s, c;
        sincosf(t, &s, &c);
        s_ct[tid] = c;
        s_st[tid] = s;
    }

    __syncthreads();

    // Stage A: per-pair precompute (2 pairs per thread), gather from LDS.
#pragma unroll
    for (int k = 0; k < NP / THREADS; ++k) {
        int p = tid + k * THREADS;
        int2 pr = pairs[p];
        float av = s_x[pr.x];
        float bv = s_x[pr.y];
        float sa = __sinf(av), ca = __cosf(av);
        float sb = __sinf(bv), cb = __cosf(bv);
        s_ca[p] = ca;
        s_w[p]  = sa * sb;
        s_z1[p] = ca * cb;
    }

    __syncthreads();

    // Phase 2: coalesced float4 output writes (7168 floats per row)
    float4* out4 = reinterpret_cast<float4*>(out + (size_t)b * OUT_PER_B);
#pragma unroll
    for (int k = 0; k < OUT_PER_B / 4 / THREADS; ++k) {   // 7 iters
        int i4 = tid + k * THREADS;       // 0..1791
        int o  = i4 * 4;
        float r[4];
#pragma unroll
        for (int j = 0; j < 4; ++j) {
            unsigned e  = (unsigned)(o + j);
            unsigned p  = e / 14u;              // magic-mul division
            unsigned rr = e - p * 14u;
            bool     q1 = rr >= 7u;
            unsigned c  = q1 ? rr - 7u : rr;
            float z0  = s_ct[c] * s_ca[p] - s_st[c] * s_w[p];
            float z   = q1 ? s_z1[p] : z0;
            r[j] = fmaf(0.5f, z, 0.5f);
        }
        out4[i4] = make_float4(r[0], r[1], r[2], r[3]);
    }
}

extern "C" void kernel_launch(void* const* d_in, const int* in_sizes, int n_in,
                              void* d_out, int out_size, void* d_ws, size_t ws_size,
                              hipStream_t stream) {
    const float* x     = (const float*)d_in[0];
    const int2*  pairs = (const int2*)d_in[1];
    const float* theta = (const float*)d_in[2];
    float*       out   = (float*)d_out;

    const int B = in_sizes[0] / NX;   // 8192
    fuzzy_qc_kernel<<<B, THREADS, 0, stream>>>(x, pairs, theta, out);
}

// Round 5
// 255.917 us; speedup vs baseline: 1.0264x; 1.0261x over previous
//
#include <hip/hip_runtime.h>

// Closed-form reduction of the 2-qubit circuit:
//   z0(b,p,c) = cos(theta_c)*cos(a) - sin(theta_c)*sin(a)*sin(b)
//   z1(b,p)   = cos(a)*cos(b)                       (theta-independent)
//   out[b, p*14 + q*7 + c] = 0.5 + 0.5*z
// where a = x[b, pair[p].x], b = x[b, pair[p].y].
//
// R5 = R4 with clang ext_vector float4 (native vector type) so
// __builtin_nontemporal_load/store accept the pointer; HIP's float4 is a
// struct and is rejected. nt store: output is write-once (235 MB), skip L2
// allocation. nt load for the once-read x row.

typedef float f32x4 __attribute__((ext_vector_type(4)));

constexpr int NX = 1024;            // flattened features per batch row
constexpr int NP = 512;             // pairs
constexpr int NC = 7;               // classes
constexpr int OUT_PER_B = NP * 2 * NC;  // 7168
constexpr int THREADS = 256;

__global__ __launch_bounds__(THREADS) void fuzzy_qc_kernel(
    const float* __restrict__ x,
    const int2*  __restrict__ pairs,
    const float* __restrict__ theta,
    float*       __restrict__ out)
{
    __shared__ float s_x[NX];    // staged input row (4 KB)
    __shared__ float s_ca[NP];   // cos(a)
    __shared__ float s_w[NP];    // sin(a)*sin(b)
    __shared__ float s_z1[NP];   // cos(a)*cos(b)
    __shared__ float s_ct[NC];   // cos(theta)
    __shared__ float s_st[NC];   // sin(theta)

    const int tid = threadIdx.x;
    const int b   = blockIdx.x;
    const float* xrow = x + (size_t)b * NX;

    // Coalesced row load -> LDS: 256 lanes x one float4 = 1024 floats.
    // nt: row is read exactly once chip-wide; don't pollute L2.
    f32x4 xv = __builtin_nontemporal_load(
        reinterpret_cast<const f32x4*>(xrow) + tid);
    reinterpret_cast<f32x4*>(s_x)[tid] = xv;

    // theta sincos (libm; only 7 lanes, arbitrary range) -> LDS
    if (tid < NC) {
        float t = theta[tid];
        float s, c;
        sincosf(t, &s, &c);
        s_ct[tid] = c;
        s_st[tid] = s;
    }

    __syncthreads();

    // Stage A: per-pair precompute (2 pairs per thread), gather from LDS.
#pragma unroll
    for (int k = 0; k < NP / THREADS; ++k) {
        int p = tid + k * THREADS;
        int2 pr = pairs[p];
        float av = s_x[pr.x];
        float bv = s_x[pr.y];
        float sa = __sinf(av), ca = __cosf(av);
        float sb = __sinf(bv), cb = __cosf(bv);
        s_ca[p] = ca;
        s_w[p]  = sa * sb;
        s_z1[p] = ca * cb;
    }

    __syncthreads();

    // Phase 2: coalesced nontemporal float4 writes (7168 floats per row)
    f32x4* out4 = reinterpret_cast<f32x4*>(out + (size_t)b * OUT_PER_B);
#pragma unroll
    for (int k = 0; k < OUT_PER_B / 4 / THREADS; ++k) {   // 7 iters
        int i4 = tid + k * THREADS;       // 0..1791
        int o  = i4 * 4;
        f32x4 r;
#pragma unroll
        for (int j = 0; j < 4; ++j) {
            unsigned e  = (unsigned)(o + j);
            unsigned p  = e / 14u;              // magic-mul division
            unsigned rr = e - p * 14u;
            bool     q1 = rr >= 7u;
            unsigned c  = q1 ? rr - 7u : rr;
            float z0  = s_ct[c] * s_ca[p] - s_st[c] * s_w[p];
            float z   = q1 ? s_z1[p] : z0;
            r[j] = fmaf(0.5f, z, 0.5f);
        }
        __builtin_nontemporal_store(r, out4 + i4);
    }
}

extern "C" void kernel_launch(void* const* d_in, const int* in_sizes, int n_in,
                              void* d_out, int out_size, void* d_ws, size_t ws_size,
                              hipStream_t stream) {
    const float* x     = (const float*)d_in[0];
    const int2*  pairs = (const int2*)d_in[1];
    const float* theta = (const float*)d_in[2];
    float*       out   = (float*)d_out;

    const int B = in_sizes[0] / NX;   // 8192
    fuzzy_qc_kernel<<<B, THREADS, 0, stream>>>(x, pairs, theta, out);
}